// Round 6
// baseline (611.812 us; speedup 1.0000x reference)
//
#include <hip/hip_runtime.h>
#include <math.h>

// ---------------------------------------------------------------------------
// TopoPoolNet: GCN(128->64) -> GCN(64->64) -> sigmoid score gate ->
//              per-graph max||mean pool -> MLP(128->64->2)
//
// Round-4/5: agg was latency-bound (VALUBusy 33%, HBM 40%, occ 77%).
//  * agg: 4 nodes/wave, 16 lanes x float4 each -> 4 rows gathered per issue,
//    unroll 4 -> 16 outstanding row-gathers per wave, 4 indep FMA chains/lane.
//  * tpn_norm deleted: dis[row] folded into GEMM epilogue (Y[n]=dis[n]*XW[n]),
//    dis[col] stays in agg epilogue.
//  * non-temporal loads/stores on streaming buffers so L2 keeps the gather
//    working set (Hin). (R5: use clang ext_vector for nt f4 store --
//    __builtin_nontemporal_store rejects HIP_vector_type.)
// ---------------------------------------------------------------------------

#define TPN_BLK 256
#define P1_EPT  16                 // edges per thread in bin pass
#define P1_CHUNK (TPN_BLK * P1_EPT)  // 4096 edges per block
#define NB_MAX  512
#define BCAP    12288              // per-bin capacity (mean ~8184)

typedef __attribute__((ext_vector_type(4))) float f32x4;

static __device__ __forceinline__ uint2 ntload_u2(const uint2* p) {
    unsigned long long v = __builtin_nontemporal_load((const unsigned long long*)p);
    uint2 r; r.x = (unsigned)v; r.y = (unsigned)(v >> 32); return r;
}
static __device__ __forceinline__ void ntstore_u2(uint2* p, uint2 v) {
    unsigned long long u = ((unsigned long long)v.y << 32) | v.x;
    __builtin_nontemporal_store(u, (unsigned long long*)p);
}
static __device__ __forceinline__ void ntstore_f4(float* p, float4 v) {
    f32x4 u = {v.x, v.y, v.z, v.w};
    __builtin_nontemporal_store(u, (f32x4*)p);
}

// ---- pass 1: bin edges by destination high bits ----------------------------
__global__ void tpn_bin(const int* __restrict__ ei, const float* __restrict__ ew,
                        int* __restrict__ binCur, uint2* __restrict__ binned,
                        int E, int NB) {
    __shared__ int hist[NB_MAX];
    __shared__ int rank[NB_MAX];
    int tid = threadIdx.x;
    for (int b = tid; b < NB; b += TPN_BLK) { hist[b] = 0; rank[b] = 0; }
    __syncthreads();

    int base = blockIdx.x * P1_CHUNK;
    uint2 ed[P1_EPT];
    int   bn[P1_EPT];
    #pragma unroll
    for (int j = 0; j < P1_EPT; ++j) {
        int e = base + tid + j * TPN_BLK;
        bn[j] = -1;
        if (e < E) {
            int r = ei[e], c = ei[E + e];
            float w = ew[e];
            int b = c >> 8;
            bn[j] = b;
            ed[j] = make_uint2((unsigned)r | ((unsigned)(c & 255) << 17),
                               __float_as_uint(w));
            atomicAdd(&hist[b], 1);
        }
    }
    __syncthreads();
    for (int b = tid; b < NB; b += TPN_BLK) {
        int h = hist[b];
        hist[b] = (h > 0) ? atomicAdd(&binCur[b], h) : 0;
    }
    __syncthreads();
    #pragma unroll
    for (int j = 0; j < P1_EPT; ++j) {
        if (bn[j] >= 0) {
            int p = hist[bn[j]] + atomicAdd(&rank[bn[j]], 1);
            if (p < BCAP) ntstore_u2(&binned[(size_t)bn[j] * BCAP + p], ed[j]);
        }
    }
}

// ---- exclusive scan of bin counts (single block) ---------------------------
__global__ void tpn_binscan(const int* __restrict__ binCur, int* __restrict__ binOff,
                            int NB) {
    __shared__ int sh[NB_MAX];
    int t = threadIdx.x;
    int v = (t < NB) ? min(binCur[t], BCAP) : 0;
    sh[t] = v;
    __syncthreads();
    for (int st = 1; st < NB_MAX; st <<= 1) {
        int u = (t >= st) ? sh[t - st] : 0;
        __syncthreads();
        sh[t] += u;
        __syncthreads();
    }
    if (t < NB) binOff[t] = sh[t] - v;
}

// ---- pass 2: per-bin packed CSR build + dis --------------------------------
__global__ void tpn_build(const uint2* __restrict__ binned, const int* __restrict__ binCur,
                          const int* __restrict__ binOff, uint2* __restrict__ packed,
                          int* __restrict__ off, int* __restrict__ cnt,
                          float* __restrict__ dis, int N) {
    __shared__ int   lcnt[256];
    __shared__ int   loff[256];
    __shared__ int   lrank[256];
    __shared__ int   lincl[256];
    __shared__ float ldeg[256];
    int b = blockIdx.x, tid = threadIdx.x;
    int m = min(binCur[b], BCAP);
    const uint2* src = binned + (size_t)b * BCAP;
    lcnt[tid] = 0; lrank[tid] = 0; ldeg[tid] = 0.0f;
    __syncthreads();
    for (int i = tid; i < m; i += 256) {
        uint2 u = ntload_u2(&src[i]);
        int ln = u.x >> 17;
        atomicAdd(&lcnt[ln], 1);
        atomicAdd(&ldeg[ln], __uint_as_float(u.y));
    }
    __syncthreads();
    lincl[tid] = lcnt[tid];
    __syncthreads();
    for (int st = 1; st < 256; st <<= 1) {
        int u = (tid >= st) ? lincl[tid - st] : 0;
        __syncthreads();
        lincl[tid] += u;
        __syncthreads();
    }
    int excl = lincl[tid] - lcnt[tid];
    loff[tid] = excl;
    int node = (b << 8) + tid;
    if (node < N) {
        off[node] = binOff[b] + excl;
        cnt[node] = lcnt[tid];
        float s = ldeg[tid];
        dis[node] = (s > 0.0f) ? rsqrtf(fmaxf(s, 1e-12f)) : 0.0f;
    }
    __syncthreads();
    int gbase = binOff[b];
    for (int i = tid; i < m; i += 256) {
        uint2 u = ntload_u2(&src[i]);
        int ln = u.x >> 17;
        int rk = atomicAdd(&lrank[ln], 1);
        ntstore_u2(&packed[gbase + loff[ln] + rk], make_uint2(u.x & 0x1FFFF, u.y));
    }
}

// ---- tiled GEMM: Y[n,f] = dis[n] * sum_k X[n,k]*W[k,f]; 64x64 tile ---------
// K must be a multiple of 64 (128 or 64 here).
__global__ __launch_bounds__(256, 4)
void tpn_gemm_t(const float* __restrict__ X, const float* __restrict__ W,
                const float* __restrict__ dis, float* __restrict__ Y,
                int N, int K) {
    __shared__ float sX[64][68];
    __shared__ float sW[64][64];
    const int t  = threadIdx.x;
    const int r  = t >> 4;
    const int cc = t & 15;
    const int fg = t & 15;
    const int ng = t >> 4;
    const int nb = blockIdx.x * 64;

    float acc[4][4] = {{0.f}};

    for (int kc = 0; kc < K; kc += 64) {
        __syncthreads();
        #pragma unroll
        for (int p = 0; p < 4; ++p) {
            int n = nb + r + p * 16;
            int ns = (n < N) ? n : (N - 1);
            float4 v = *reinterpret_cast<const float4*>(X + (size_t)ns * K + kc + 4 * cc);
            *reinterpret_cast<float4*>(&sX[r + p * 16][4 * cc]) = v;
        }
        #pragma unroll
        for (int p = 0; p < 4; ++p) {
            int k = kc + r + p * 16;
            float4 v = *reinterpret_cast<const float4*>(W + (size_t)k * 64 + 4 * cc);
            *reinterpret_cast<float4*>(&sW[r + p * 16][4 * cc]) = v;
        }
        __syncthreads();
        #pragma unroll 4
        for (int k = 0; k < 64; ++k) {
            float4 wv = *reinterpret_cast<const float4*>(&sW[k][4 * fg]);
            float x0 = sX[4 * ng + 0][k];
            float x1 = sX[4 * ng + 1][k];
            float x2 = sX[4 * ng + 2][k];
            float x3 = sX[4 * ng + 3][k];
            acc[0][0] = fmaf(x0, wv.x, acc[0][0]);
            acc[0][1] = fmaf(x0, wv.y, acc[0][1]);
            acc[0][2] = fmaf(x0, wv.z, acc[0][2]);
            acc[0][3] = fmaf(x0, wv.w, acc[0][3]);
            acc[1][0] = fmaf(x1, wv.x, acc[1][0]);
            acc[1][1] = fmaf(x1, wv.y, acc[1][1]);
            acc[1][2] = fmaf(x1, wv.z, acc[1][2]);
            acc[1][3] = fmaf(x1, wv.w, acc[1][3]);
            acc[2][0] = fmaf(x2, wv.x, acc[2][0]);
            acc[2][1] = fmaf(x2, wv.y, acc[2][1]);
            acc[2][2] = fmaf(x2, wv.z, acc[2][2]);
            acc[2][3] = fmaf(x2, wv.w, acc[2][3]);
            acc[3][0] = fmaf(x3, wv.x, acc[3][0]);
            acc[3][1] = fmaf(x3, wv.y, acc[3][1]);
            acc[3][2] = fmaf(x3, wv.z, acc[3][2]);
            acc[3][3] = fmaf(x3, wv.w, acc[3][3]);
        }
    }
    #pragma unroll
    for (int i = 0; i < 4; ++i) {
        int n = nb + 4 * ng + i;
        if (n < N) {
            float d = dis[n];
            float4 v = make_float4(acc[i][0] * d, acc[i][1] * d,
                                   acc[i][2] * d, acc[i][3] * d);
            *reinterpret_cast<float4*>(Y + (size_t)n * 64 + 4 * fg) = v;
        }
    }
}

// ---- aggregate: 4 nodes/wave, 16 lanes x float4 per node -------------------
// Hin rows are pre-scaled by dis[row] (GEMM epilogue); epilogue applies
// dis[col] then bias/relu (+ optional sigmoid score gate).
template <bool FUSE_SCORE>
__global__ __launch_bounds__(256)
void tpn_agg4(const uint2* __restrict__ packed, const int* __restrict__ off,
              const int* __restrict__ cnt, const float* __restrict__ dis,
              const float* __restrict__ Hin, const float* __restrict__ bias,
              const float* __restrict__ pw, const float* __restrict__ pb,
              float* __restrict__ Hout, int N) {
    int gt   = blockIdx.x * blockDim.x + threadIdx.x;
    int node = gt >> 4;            // 16 lanes per node
    int fl   = threadIdx.x & 15;   // features 4*fl .. 4*fl+3
    if (node >= N) return;
    int start = off[node], n = cnt[node];
    const uint2* b = packed + start;
    const float* hp = Hin + 4 * fl;

    float4 a0 = {0.f, 0.f, 0.f, 0.f};
    float4 a1 = {0.f, 0.f, 0.f, 0.f};
    int j = 0;
    for (; j + 3 < n; j += 4) {
        uint2 p0 = b[j + 0];
        uint2 p1 = b[j + 1];
        uint2 p2 = b[j + 2];
        uint2 p3 = b[j + 3];
        float4 v0 = *reinterpret_cast<const float4*>(hp + (size_t)p0.x * 64);
        float4 v1 = *reinterpret_cast<const float4*>(hp + (size_t)p1.x * 64);
        float4 v2 = *reinterpret_cast<const float4*>(hp + (size_t)p2.x * 64);
        float4 v3 = *reinterpret_cast<const float4*>(hp + (size_t)p3.x * 64);
        float w0 = __uint_as_float(p0.y), w1 = __uint_as_float(p1.y);
        float w2 = __uint_as_float(p2.y), w3 = __uint_as_float(p3.y);
        a0.x = fmaf(w0, v0.x, a0.x); a0.y = fmaf(w0, v0.y, a0.y);
        a0.z = fmaf(w0, v0.z, a0.z); a0.w = fmaf(w0, v0.w, a0.w);
        a1.x = fmaf(w1, v1.x, a1.x); a1.y = fmaf(w1, v1.y, a1.y);
        a1.z = fmaf(w1, v1.z, a1.z); a1.w = fmaf(w1, v1.w, a1.w);
        a0.x = fmaf(w2, v2.x, a0.x); a0.y = fmaf(w2, v2.y, a0.y);
        a0.z = fmaf(w2, v2.z, a0.z); a0.w = fmaf(w2, v2.w, a0.w);
        a1.x = fmaf(w3, v3.x, a1.x); a1.y = fmaf(w3, v3.y, a1.y);
        a1.z = fmaf(w3, v3.z, a1.z); a1.w = fmaf(w3, v3.w, a1.w);
    }
    for (; j < n; ++j) {
        uint2 p = b[j];
        float4 v = *reinterpret_cast<const float4*>(hp + (size_t)p.x * 64);
        float w = __uint_as_float(p.y);
        a0.x = fmaf(w, v.x, a0.x); a0.y = fmaf(w, v.y, a0.y);
        a0.z = fmaf(w, v.z, a0.z); a0.w = fmaf(w, v.w, a0.w);
    }
    float dc = dis[node];
    const float4 bv = *reinterpret_cast<const float4*>(bias + 4 * fl);
    float4 h;
    h.x = fmaxf(fmaf(a0.x + a1.x, dc, bv.x), 0.0f);
    h.y = fmaxf(fmaf(a0.y + a1.y, dc, bv.y), 0.0f);
    h.z = fmaxf(fmaf(a0.z + a1.z, dc, bv.z), 0.0f);
    h.w = fmaxf(fmaf(a0.w + a1.w, dc, bv.w), 0.0f);
    if (FUSE_SCORE) {
        const float4 pv = *reinterpret_cast<const float4*>(pw + 4 * fl);
        float t = h.x * pv.x + h.y * pv.y + h.z * pv.z + h.w * pv.w;
        #pragma unroll
        for (int m = 8; m > 0; m >>= 1) t += __shfl_xor(t, m, 16);
        float s = 1.0f / (1.0f + expf(-(t + pb[0])));
        h.x *= s; h.y *= s; h.z *= s; h.w *= s;
    }
    ntstore_f4(Hout + (size_t)node * 64 + 4 * fl, h);
}

// ---- per-graph max || mean pooling (batch sorted) --------------------------
__global__ void tpn_pool(const float* __restrict__ Hs, const int* __restrict__ batch,
                         int N, float* __restrict__ Gf) {
    int g = blockIdx.x;
    int s, e;
    {
        int lo = 0, hi = N;
        while (lo < hi) { int mid = (lo + hi) >> 1; if (batch[mid] < g) lo = mid + 1; else hi = mid; }
        s = lo;
        lo = 0; hi = N;
        while (lo < hi) { int mid = (lo + hi) >> 1; if (batch[mid] < g + 1) lo = mid + 1; else hi = mid; }
        e = lo;
    }
    int lane = threadIdx.x & 63;
    int w = threadIdx.x >> 6;  // 0..3
    float mx = -3.4e38f, sm = 0.0f;
    for (int i = s + w; i < e; i += 4) {
        float v = Hs[(size_t)i * 64 + lane];
        mx = fmaxf(mx, v);
        sm += v;
    }
    __shared__ float shm[4][64], shs[4][64];
    shm[w][lane] = mx; shs[w][lane] = sm;
    __syncthreads();
    if (w == 0) {
        mx = fmaxf(fmaxf(shm[0][lane], shm[1][lane]), fmaxf(shm[2][lane], shm[3][lane]));
        sm = shs[0][lane] + shs[1][lane] + shs[2][lane] + shs[3][lane];
        float c = (float)(e - s);
        float inv = 1.0f / fmaxf(c, 1.0f);
        Gf[g * 128 + lane]      = mx;
        Gf[g * 128 + 64 + lane] = sm * inv;
    }
}

// ---- final MLP: out = relu(G @ lw1 + lb1) @ lw2 + lb2 ----------------------
__global__ void tpn_mlp(const float* __restrict__ Gf, const float* __restrict__ lw1,
                        const float* __restrict__ lb1, const float* __restrict__ lw2,
                        const float* __restrict__ lb2, float* __restrict__ out,
                        int G, int C) {
    int wid = (blockIdx.x * blockDim.x + threadIdx.x) >> 6;
    int lane = threadIdx.x & 63;
    if (wid >= G) return;
    const float* gr = Gf + (size_t)wid * 128;
    float acc = lb1[lane];
    for (int k = 0; k < 128; k += 4) {
        float4 gv = *reinterpret_cast<const float4*>(gr + k);
        acc = fmaf(gv.x, lw1[(k + 0) * 64 + lane], acc);
        acc = fmaf(gv.y, lw1[(k + 1) * 64 + lane], acc);
        acc = fmaf(gv.z, lw1[(k + 2) * 64 + lane], acc);
        acc = fmaf(gv.w, lw1[(k + 3) * 64 + lane], acc);
    }
    float t = fmaxf(acc, 0.0f);
    for (int c = 0; c < C; ++c) {
        float v = t * lw2[lane * C + c];
        #pragma unroll
        for (int m = 32; m > 0; m >>= 1) v += __shfl_xor(v, m);
        if (lane == 0) out[wid * C + c] = v + lb2[c];
    }
}

// ---------------------------------------------------------------------------
extern "C" void kernel_launch(void* const* d_in, const int* in_sizes, int n_in,
                              void* d_out, int out_size, void* d_ws, size_t ws_size,
                              hipStream_t stream) {
    const float* x   = (const float*)d_in[0];
    const int*   ei  = (const int*)  d_in[1];
    const float* ew  = (const float*)d_in[2];
    const int*   bat = (const int*)  d_in[3];
    const float* W1  = (const float*)d_in[5];
    const float* b1  = (const float*)d_in[6];
    const float* W2  = (const float*)d_in[7];
    const float* b2  = (const float*)d_in[8];
    const float* pw  = (const float*)d_in[9];
    const float* pb  = (const float*)d_in[10];
    const float* lw1 = (const float*)d_in[11];
    const float* lb1 = (const float*)d_in[12];
    const float* lw2 = (const float*)d_in[13];
    const float* lb2 = (const float*)d_in[14];
    float* out = (float*)d_out;

    const int N  = in_sizes[3];
    const int E  = in_sizes[2];
    const int IN = in_sizes[0] / N;   // 128
    const int C  = in_sizes[14];      // 2
    const int G  = out_size / C;      // 128
    const int NB = (N + 255) >> 8;    // bins of 256 nodes

    // ---- workspace layout ----
    char* ws = (char*)d_ws;
    size_t o = 0;
    auto alloc = [&](size_t bytes) { void* p = ws + o; o = (o + bytes + 255) & ~(size_t)255; return p; };
    int*   off    = (int*)  alloc((size_t)N * 4);
    int*   cnt    = (int*)  alloc((size_t)N * 4);
    float* dis    = (float*)alloc((size_t)N * 4);
    int*   binCur = (int*)  alloc((size_t)NB_MAX * 4);
    int*   binOff = (int*)  alloc((size_t)NB_MAX * 4);
    float* Gf     = (float*)alloc((size_t)G * 128 * 4);
    uint2* packed = (uint2*)alloc((size_t)E * 8);
    float* hA     = (float*)alloc((size_t)N * 64 * 4);
    float* hB     = (float*)alloc((size_t)N * 64 * 4);
    // binned is dead after tpn_build -> alias it over hA/hB
    uint2* binned = (uint2*)hA;
    (void)n_in; (void)ws_size;

    (void)hipMemsetAsync(binCur, 0, (size_t)NB_MAX * 4, stream);

    const int p1b   = (E + P1_CHUNK - 1) / P1_CHUNK;
    const int ggrid = (N + 63) / 64;                   // gemm tiles
    const int agrid = ((N * 16) + TPN_BLK - 1) / TPN_BLK;  // agg: 16 thr/node

    // CSR build: bin -> scan -> build  (norm folded into GEMM epilogue)
    tpn_bin<<<p1b, TPN_BLK, 0, stream>>>(ei, ew, binCur, binned, E, NB);
    tpn_binscan<<<1, NB_MAX, 0, stream>>>(binCur, binOff, NB);
    tpn_build<<<NB, 256, 0, stream>>>(binned, binCur, binOff, packed, off, cnt, dis, N);

    // layer 1: hA = dis * (x @ W1) ; hB = relu(dis*agg(hA) + b1)
    tpn_gemm_t<<<ggrid, 256, 0, stream>>>(x, W1, dis, hA, N, IN);
    tpn_agg4<false><<<agrid, TPN_BLK, 0, stream>>>(packed, off, cnt, dis, hA, b1, pw, pb, hB, N);

    // layer 2: hA = dis * (hB @ W2) ; hB = score-gated relu(dis*agg(hA) + b2)
    tpn_gemm_t<<<ggrid, 256, 0, stream>>>(hB, W2, dis, hA, N, 64);
    tpn_agg4<true><<<agrid, TPN_BLK, 0, stream>>>(packed, off, cnt, dis, hA, b2, pw, pb, hB, N);

    // pooling + MLP head
    tpn_pool<<<G, TPN_BLK, 0, stream>>>(hB, bat, N, Gf);
    tpn_mlp<<<(G * 64 + TPN_BLK - 1) / TPN_BLK, TPN_BLK, 0, stream>>>(Gf, lw1, lb1, lw2, lb2, out, G, C);
}

// Round 7
// 433.872 us; speedup vs baseline: 1.4101x; 1.4101x over previous
//
#include <hip/hip_runtime.h>
#include <math.h>

// ---------------------------------------------------------------------------
// TopoPoolNet: GCN(128->64) -> GCN(64->64) -> sigmoid score gate ->
//              per-graph max||mean pool -> MLP(128->64->2)
//
// Round-7: tpn_bin was the top cost (135us, WRITE_SIZE 104MB for 25.6MB
// payload -- uncoalesced 8B scatter, 4x sector amplification). Now a
// block-level LDS counting sort: histogram -> scan -> reserve -> LDS scatter
// -> COALESCED global writeout. All nontemporal hints removed (they defeated
// write-combining and forced HBM round-trips). Agg reverted to 64-lane
// wave-per-node (known-good) with unroll 8 / 4 accumulators for 2x MLP.
// ---------------------------------------------------------------------------

#define TPN_BLK 256
#define P1_EPT  16                   // edges per thread in bin pass
#define P1_CHUNK (TPN_BLK * P1_EPT)  // 4096 edges per block
#define NB_MAX  512
#define BCAP    12288                // per-bin capacity (mean ~8184)

// ---- pass 1: block-level counting sort by bin (col>>8), coalesced out -----
__global__ __launch_bounds__(256)
void tpn_bin(const int* __restrict__ ei, const float* __restrict__ ew,
             int* __restrict__ binCur, uint2* __restrict__ binned,
             int E, int NB) {
    __shared__ uint2          sbuf[P1_CHUNK];      // 32 KB
    __shared__ unsigned short sbin[P1_CHUNK];      // 8 KB
    __shared__ int hist[NB_MAX];
    __shared__ int loff[NB_MAX];
    __shared__ int lrank[NB_MAX];
    __shared__ int gbase[NB_MAX];
    __shared__ int ssc[256];

    int tid = threadIdx.x;
    for (int b = tid; b < NB_MAX; b += 256) { hist[b] = 0; lrank[b] = 0; }
    __syncthreads();

    int base = blockIdx.x * P1_CHUNK;
    uint2 ed[P1_EPT];
    int   bn[P1_EPT];
    #pragma unroll
    for (int j = 0; j < P1_EPT; ++j) {
        int e = base + tid + j * 256;
        bn[j] = -1;
        if (e < E) {
            int r = ei[e], c = ei[E + e];
            bn[j] = c >> 8;
            ed[j] = make_uint2((unsigned)r | ((unsigned)(c & 255) << 17),
                               __float_as_uint(ew[e]));
            atomicAdd(&hist[bn[j]], 1);
        }
    }
    __syncthreads();
    // exclusive scan of hist[0..NB_MAX) -> loff (thread t owns bins 2t, 2t+1)
    {
        int b0 = 2 * tid, b1 = 2 * tid + 1;
        int h0 = hist[b0], h1 = hist[b1];
        int s = h0 + h1;
        ssc[tid] = s;
        __syncthreads();
        for (int st = 1; st < 256; st <<= 1) {
            int v = (tid >= st) ? ssc[tid - st] : 0;
            __syncthreads();
            ssc[tid] += v;
            __syncthreads();
        }
        int pre = ssc[tid] - s;
        loff[b0] = pre;
        loff[b1] = pre + h0;
    }
    __syncthreads();
    // reserve global space per (block, bin): one far atomic each
    for (int b = tid; b < NB; b += 256) {
        int h = hist[b];
        if (h > 0) gbase[b] = atomicAdd(&binCur[b], h);
    }
    // scatter into LDS, sorted by bin
    #pragma unroll
    for (int j = 0; j < P1_EPT; ++j) {
        if (bn[j] >= 0) {
            int p = loff[bn[j]] + atomicAdd(&lrank[bn[j]], 1);
            sbuf[p] = ed[j];
            sbin[p] = (unsigned short)bn[j];
        }
    }
    __syncthreads();
    // coalesced writeout: position i belongs to bin sbin[i], local idx i-loff
    int m = min(E - base, P1_CHUNK);
    for (int i = tid; i < m; i += 256) {
        uint2 u = sbuf[i];
        int b = sbin[i];
        int dst = gbase[b] + (i - loff[b]);
        if (dst < BCAP) binned[(size_t)b * BCAP + dst] = u;
    }
}

// ---- exclusive scan of bin counts (single block) ---------------------------
__global__ void tpn_binscan(const int* __restrict__ binCur, int* __restrict__ binOff,
                            int NB) {
    __shared__ int sh[NB_MAX];
    int t = threadIdx.x;
    int v = (t < NB) ? min(binCur[t], BCAP) : 0;
    sh[t] = v;
    __syncthreads();
    for (int st = 1; st < NB_MAX; st <<= 1) {
        int u = (t >= st) ? sh[t - st] : 0;
        __syncthreads();
        sh[t] += u;
        __syncthreads();
    }
    if (t < NB) binOff[t] = sh[t] - v;
}

// ---- pass 2: per-bin packed CSR build + dis --------------------------------
__global__ void tpn_build(const uint2* __restrict__ binned, const int* __restrict__ binCur,
                          const int* __restrict__ binOff, uint2* __restrict__ packed,
                          int* __restrict__ off, int* __restrict__ cnt,
                          float* __restrict__ dis, int N) {
    __shared__ int   lcnt[256];
    __shared__ int   loff[256];
    __shared__ int   lrank[256];
    __shared__ int   lincl[256];
    __shared__ float ldeg[256];
    int b = blockIdx.x, tid = threadIdx.x;
    int m = min(binCur[b], BCAP);
    const uint2* src = binned + (size_t)b * BCAP;
    lcnt[tid] = 0; lrank[tid] = 0; ldeg[tid] = 0.0f;
    __syncthreads();
    for (int i = tid; i < m; i += 256) {
        uint2 u = src[i];
        int ln = u.x >> 17;
        atomicAdd(&lcnt[ln], 1);
        atomicAdd(&ldeg[ln], __uint_as_float(u.y));
    }
    __syncthreads();
    lincl[tid] = lcnt[tid];
    __syncthreads();
    for (int st = 1; st < 256; st <<= 1) {
        int u = (tid >= st) ? lincl[tid - st] : 0;
        __syncthreads();
        lincl[tid] += u;
        __syncthreads();
    }
    int excl = lincl[tid] - lcnt[tid];
    loff[tid] = excl;
    int node = (b << 8) + tid;
    if (node < N) {
        off[node] = binOff[b] + excl;
        cnt[node] = lcnt[tid];
        float s = ldeg[tid];
        dis[node] = (s > 0.0f) ? rsqrtf(fmaxf(s, 1e-12f)) : 0.0f;
    }
    __syncthreads();
    int gbase = binOff[b];
    for (int i = tid; i < m; i += 256) {
        uint2 u = src[i];
        int ln = u.x >> 17;
        int rk = atomicAdd(&lrank[ln], 1);
        packed[gbase + loff[ln] + rk] = make_uint2(u.x & 0x1FFFF, u.y);
    }
}

// ---- tiled GEMM: Y[n,f] = dis[n] * sum_k X[n,k]*W[k,f]; 64x64 tile ---------
// K must be a multiple of 64 (128 or 64 here).
__global__ __launch_bounds__(256, 4)
void tpn_gemm_t(const float* __restrict__ X, const float* __restrict__ W,
                const float* __restrict__ dis, float* __restrict__ Y,
                int N, int K) {
    __shared__ float sX[64][68];
    __shared__ float sW[64][64];
    const int t  = threadIdx.x;
    const int r  = t >> 4;
    const int cc = t & 15;
    const int fg = t & 15;
    const int ng = t >> 4;
    const int nb = blockIdx.x * 64;

    float acc[4][4] = {{0.f}};

    for (int kc = 0; kc < K; kc += 64) {
        __syncthreads();
        #pragma unroll
        for (int p = 0; p < 4; ++p) {
            int n = nb + r + p * 16;
            int ns = (n < N) ? n : (N - 1);
            float4 v = *reinterpret_cast<const float4*>(X + (size_t)ns * K + kc + 4 * cc);
            *reinterpret_cast<float4*>(&sX[r + p * 16][4 * cc]) = v;
        }
        #pragma unroll
        for (int p = 0; p < 4; ++p) {
            int k = kc + r + p * 16;
            float4 v = *reinterpret_cast<const float4*>(W + (size_t)k * 64 + 4 * cc);
            *reinterpret_cast<float4*>(&sW[r + p * 16][4 * cc]) = v;
        }
        __syncthreads();
        #pragma unroll 4
        for (int k = 0; k < 64; ++k) {
            float4 wv = *reinterpret_cast<const float4*>(&sW[k][4 * fg]);
            float x0 = sX[4 * ng + 0][k];
            float x1 = sX[4 * ng + 1][k];
            float x2 = sX[4 * ng + 2][k];
            float x3 = sX[4 * ng + 3][k];
            acc[0][0] = fmaf(x0, wv.x, acc[0][0]);
            acc[0][1] = fmaf(x0, wv.y, acc[0][1]);
            acc[0][2] = fmaf(x0, wv.z, acc[0][2]);
            acc[0][3] = fmaf(x0, wv.w, acc[0][3]);
            acc[1][0] = fmaf(x1, wv.x, acc[1][0]);
            acc[1][1] = fmaf(x1, wv.y, acc[1][1]);
            acc[1][2] = fmaf(x1, wv.z, acc[1][2]);
            acc[1][3] = fmaf(x1, wv.w, acc[1][3]);
            acc[2][0] = fmaf(x2, wv.x, acc[2][0]);
            acc[2][1] = fmaf(x2, wv.y, acc[2][1]);
            acc[2][2] = fmaf(x2, wv.z, acc[2][2]);
            acc[2][3] = fmaf(x2, wv.w, acc[2][3]);
            acc[3][0] = fmaf(x3, wv.x, acc[3][0]);
            acc[3][1] = fmaf(x3, wv.y, acc[3][1]);
            acc[3][2] = fmaf(x3, wv.z, acc[3][2]);
            acc[3][3] = fmaf(x3, wv.w, acc[3][3]);
        }
    }
    #pragma unroll
    for (int i = 0; i < 4; ++i) {
        int n = nb + 4 * ng + i;
        if (n < N) {
            float d = dis[n];
            float4 v = make_float4(acc[i][0] * d, acc[i][1] * d,
                                   acc[i][2] * d, acc[i][3] * d);
            *reinterpret_cast<float4*>(Y + (size_t)n * 64 + 4 * fg) = v;
        }
    }
}

// ---- aggregate: wave per node, lane = feature, unroll 8, 4 acc chains ------
// Hin rows pre-scaled by dis[row] (GEMM epilogue); epilogue applies dis[col]
// then bias/relu (+ optional sigmoid score gate).
template <bool FUSE_SCORE>
__global__ __launch_bounds__(256)
void tpn_agg(const uint2* __restrict__ packed, const int* __restrict__ off,
             const int* __restrict__ cnt, const float* __restrict__ dis,
             const float* __restrict__ Hin, const float* __restrict__ bias,
             const float* __restrict__ pw, const float* __restrict__ pb,
             float* __restrict__ Hout, int N) {
    int wid = (blockIdx.x * blockDim.x + threadIdx.x) >> 6;
    int lane = threadIdx.x & 63;
    if (wid >= N) return;
    int start = off[wid], n = cnt[wid];
    const uint2* b = packed + start;
    float a0 = 0.f, a1 = 0.f, a2 = 0.f, a3 = 0.f;
    int j = 0;
    for (; j + 7 < n; j += 8) {
        uint2 p0 = b[j + 0], p1 = b[j + 1], p2 = b[j + 2], p3 = b[j + 3];
        uint2 p4 = b[j + 4], p5 = b[j + 5], p6 = b[j + 6], p7 = b[j + 7];
        float v0 = Hin[(size_t)p0.x * 64 + lane];
        float v1 = Hin[(size_t)p1.x * 64 + lane];
        float v2 = Hin[(size_t)p2.x * 64 + lane];
        float v3 = Hin[(size_t)p3.x * 64 + lane];
        float v4 = Hin[(size_t)p4.x * 64 + lane];
        float v5 = Hin[(size_t)p5.x * 64 + lane];
        float v6 = Hin[(size_t)p6.x * 64 + lane];
        float v7 = Hin[(size_t)p7.x * 64 + lane];
        a0 = fmaf(__uint_as_float(p0.y), v0, a0);
        a1 = fmaf(__uint_as_float(p1.y), v1, a1);
        a2 = fmaf(__uint_as_float(p2.y), v2, a2);
        a3 = fmaf(__uint_as_float(p3.y), v3, a3);
        a0 = fmaf(__uint_as_float(p4.y), v4, a0);
        a1 = fmaf(__uint_as_float(p5.y), v5, a1);
        a2 = fmaf(__uint_as_float(p6.y), v6, a2);
        a3 = fmaf(__uint_as_float(p7.y), v7, a3);
    }
    for (; j < n; ++j) {
        uint2 p = b[j];
        a0 = fmaf(__uint_as_float(p.y), Hin[(size_t)p.x * 64 + lane], a0);
    }
    float acc = (a0 + a1) + (a2 + a3);
    float h = fmaxf(fmaf(acc, dis[wid], bias[lane]), 0.0f);
    if (FUSE_SCORE) {
        float t = h * pw[lane];
        #pragma unroll
        for (int m = 32; m > 0; m >>= 1) t += __shfl_xor(t, m);
        float s = 1.0f / (1.0f + expf(-(t + pb[0])));
        h *= s;
    }
    Hout[(size_t)wid * 64 + lane] = h;
}

// ---- per-graph max || mean pooling (batch sorted) --------------------------
__global__ void tpn_pool(const float* __restrict__ Hs, const int* __restrict__ batch,
                         int N, float* __restrict__ Gf) {
    int g = blockIdx.x;
    int s, e;
    {
        int lo = 0, hi = N;
        while (lo < hi) { int mid = (lo + hi) >> 1; if (batch[mid] < g) lo = mid + 1; else hi = mid; }
        s = lo;
        lo = 0; hi = N;
        while (lo < hi) { int mid = (lo + hi) >> 1; if (batch[mid] < g + 1) lo = mid + 1; else hi = mid; }
        e = lo;
    }
    int lane = threadIdx.x & 63;
    int w = threadIdx.x >> 6;  // 0..3
    float mx = -3.4e38f, sm = 0.0f;
    for (int i = s + w; i < e; i += 4) {
        float v = Hs[(size_t)i * 64 + lane];
        mx = fmaxf(mx, v);
        sm += v;
    }
    __shared__ float shm[4][64], shs[4][64];
    shm[w][lane] = mx; shs[w][lane] = sm;
    __syncthreads();
    if (w == 0) {
        mx = fmaxf(fmaxf(shm[0][lane], shm[1][lane]), fmaxf(shm[2][lane], shm[3][lane]));
        sm = shs[0][lane] + shs[1][lane] + shs[2][lane] + shs[3][lane];
        float c = (float)(e - s);
        float inv = 1.0f / fmaxf(c, 1.0f);
        Gf[g * 128 + lane]      = mx;
        Gf[g * 128 + 64 + lane] = sm * inv;
    }
}

// ---- final MLP: out = relu(G @ lw1 + lb1) @ lw2 + lb2 ----------------------
__global__ void tpn_mlp(const float* __restrict__ Gf, const float* __restrict__ lw1,
                        const float* __restrict__ lb1, const float* __restrict__ lw2,
                        const float* __restrict__ lb2, float* __restrict__ out,
                        int G, int C) {
    int wid = (blockIdx.x * blockDim.x + threadIdx.x) >> 6;
    int lane = threadIdx.x & 63;
    if (wid >= G) return;
    const float* gr = Gf + (size_t)wid * 128;
    float acc = lb1[lane];
    for (int k = 0; k < 128; k += 4) {
        float4 gv = *reinterpret_cast<const float4*>(gr + k);
        acc = fmaf(gv.x, lw1[(k + 0) * 64 + lane], acc);
        acc = fmaf(gv.y, lw1[(k + 1) * 64 + lane], acc);
        acc = fmaf(gv.z, lw1[(k + 2) * 64 + lane], acc);
        acc = fmaf(gv.w, lw1[(k + 3) * 64 + lane], acc);
    }
    float t = fmaxf(acc, 0.0f);
    for (int c = 0; c < C; ++c) {
        float v = t * lw2[lane * C + c];
        #pragma unroll
        for (int m = 32; m > 0; m >>= 1) v += __shfl_xor(v, m);
        if (lane == 0) out[wid * C + c] = v + lb2[c];
    }
}

// ---------------------------------------------------------------------------
extern "C" void kernel_launch(void* const* d_in, const int* in_sizes, int n_in,
                              void* d_out, int out_size, void* d_ws, size_t ws_size,
                              hipStream_t stream) {
    const float* x   = (const float*)d_in[0];
    const int*   ei  = (const int*)  d_in[1];
    const float* ew  = (const float*)d_in[2];
    const int*   bat = (const int*)  d_in[3];
    const float* W1  = (const float*)d_in[5];
    const float* b1  = (const float*)d_in[6];
    const float* W2  = (const float*)d_in[7];
    const float* b2  = (const float*)d_in[8];
    const float* pw  = (const float*)d_in[9];
    const float* pb  = (const float*)d_in[10];
    const float* lw1 = (const float*)d_in[11];
    const float* lb1 = (const float*)d_in[12];
    const float* lw2 = (const float*)d_in[13];
    const float* lb2 = (const float*)d_in[14];
    float* out = (float*)d_out;

    const int N  = in_sizes[3];
    const int E  = in_sizes[2];
    const int IN = in_sizes[0] / N;   // 128
    const int C  = in_sizes[14];      // 2
    const int G  = out_size / C;      // 128
    const int NB = (N + 255) >> 8;    // bins of 256 nodes

    // ---- workspace layout ----
    char* ws = (char*)d_ws;
    size_t o = 0;
    auto alloc = [&](size_t bytes) { void* p = ws + o; o = (o + bytes + 255) & ~(size_t)255; return p; };
    int*   off    = (int*)  alloc((size_t)N * 4);
    int*   cnt    = (int*)  alloc((size_t)N * 4);
    float* dis    = (float*)alloc((size_t)N * 4);
    int*   binCur = (int*)  alloc((size_t)NB_MAX * 4);
    int*   binOff = (int*)  alloc((size_t)NB_MAX * 4);
    float* Gf     = (float*)alloc((size_t)G * 128 * 4);
    uint2* packed = (uint2*)alloc((size_t)E * 8);
    float* hA     = (float*)alloc((size_t)N * 64 * 4);
    float* hB     = (float*)alloc((size_t)N * 64 * 4);
    // binned is dead after tpn_build -> alias it over hA/hB
    uint2* binned = (uint2*)hA;
    (void)n_in; (void)ws_size;

    (void)hipMemsetAsync(binCur, 0, (size_t)NB_MAX * 4, stream);

    const int p1b   = (E + P1_CHUNK - 1) / P1_CHUNK;
    const int ggrid = (N + 63) / 64;                        // gemm tiles
    const int agrid = (N * 64 + TPN_BLK - 1) / TPN_BLK;     // wave per node

    // CSR build: bin (LDS sort, coalesced) -> scan -> build
    tpn_bin<<<p1b, TPN_BLK, 0, stream>>>(ei, ew, binCur, binned, E, NB);
    tpn_binscan<<<1, NB_MAX, 0, stream>>>(binCur, binOff, NB);
    tpn_build<<<NB, 256, 0, stream>>>(binned, binCur, binOff, packed, off, cnt, dis, N);

    // layer 1: hA = dis * (x @ W1) ; hB = relu(dis*agg(hA) + b1)
    tpn_gemm_t<<<ggrid, 256, 0, stream>>>(x, W1, dis, hA, N, IN);
    tpn_agg<false><<<agrid, TPN_BLK, 0, stream>>>(packed, off, cnt, dis, hA, b1, pw, pb, hB, N);

    // layer 2: hA = dis * (hB @ W2) ; hB = score-gated relu(dis*agg(hA) + b2)
    tpn_gemm_t<<<ggrid, 256, 0, stream>>>(hB, W2, dis, hA, N, 64);
    tpn_agg<true><<<agrid, TPN_BLK, 0, stream>>>(packed, off, cnt, dis, hA, b2, pw, pb, hB, N);

    // pooling + MLP head
    tpn_pool<<<G, TPN_BLK, 0, stream>>>(hB, bat, N, Gf);
    tpn_mlp<<<(G * 64 + TPN_BLK - 1) / TPN_BLK, TPN_BLK, 0, stream>>>(Gf, lw1, lb1, lw2, lb2, out, G, C);
}

// Round 8
// 419.223 us; speedup vs baseline: 1.4594x; 1.0349x over previous
//
#include <hip/hip_runtime.h>
#include <math.h>

// ---------------------------------------------------------------------------
// TopoPoolNet: GCN(128->64) -> GCN(64->64) -> sigmoid score gate ->
//              per-graph max||mean pool -> MLP(128->64->2)
//
// Round-8: agg was vmem-instruction-bound (1 wave-gather per edge = 256B per
// instr, 23 cyc/instr). Now quad-edge gather: one wave = one node, 16 lanes x
// float4 per edge -> one dwordx4 instruction moves 1KB covering 4 edge rows.
// 4x fewer gather instrs + 4x fewer addr calcs; shfl_xor(16/32) folds the
// 4 edge slots. Bin = LDS counting sort (R7), build/gemm/pool/mlp unchanged.
// ---------------------------------------------------------------------------

#define TPN_BLK 256
#define P1_EPT  16                   // edges per thread in bin pass
#define P1_CHUNK (TPN_BLK * P1_EPT)  // 4096 edges per block
#define NB_MAX  512
#define BCAP    12288                // per-bin capacity (mean ~8184)

// ---- pass 1: block-level counting sort by bin (col>>8), coalesced out -----
__global__ __launch_bounds__(256)
void tpn_bin(const int* __restrict__ ei, const float* __restrict__ ew,
             int* __restrict__ binCur, uint2* __restrict__ binned,
             int E, int NB) {
    __shared__ uint2          sbuf[P1_CHUNK];      // 32 KB
    __shared__ unsigned short sbin[P1_CHUNK];      // 8 KB
    __shared__ int hist[NB_MAX];
    __shared__ int loff[NB_MAX];
    __shared__ int lrank[NB_MAX];
    __shared__ int gbase[NB_MAX];
    __shared__ int ssc[256];

    int tid = threadIdx.x;
    for (int b = tid; b < NB_MAX; b += 256) { hist[b] = 0; lrank[b] = 0; }
    __syncthreads();

    int base = blockIdx.x * P1_CHUNK;
    uint2 ed[P1_EPT];
    int   bn[P1_EPT];
    #pragma unroll
    for (int j = 0; j < P1_EPT; ++j) {
        int e = base + tid + j * 256;
        bn[j] = -1;
        if (e < E) {
            int r = ei[e], c = ei[E + e];
            bn[j] = c >> 8;
            ed[j] = make_uint2((unsigned)r | ((unsigned)(c & 255) << 17),
                               __float_as_uint(ew[e]));
            atomicAdd(&hist[bn[j]], 1);
        }
    }
    __syncthreads();
    // exclusive scan of hist[0..NB_MAX) -> loff (thread t owns bins 2t, 2t+1)
    {
        int b0 = 2 * tid, b1 = 2 * tid + 1;
        int h0 = hist[b0], h1 = hist[b1];
        int s = h0 + h1;
        ssc[tid] = s;
        __syncthreads();
        for (int st = 1; st < 256; st <<= 1) {
            int v = (tid >= st) ? ssc[tid - st] : 0;
            __syncthreads();
            ssc[tid] += v;
            __syncthreads();
        }
        int pre = ssc[tid] - s;
        loff[b0] = pre;
        loff[b1] = pre + h0;
    }
    __syncthreads();
    // reserve global space per (block, bin): one far atomic each
    for (int b = tid; b < NB; b += 256) {
        int h = hist[b];
        if (h > 0) gbase[b] = atomicAdd(&binCur[b], h);
    }
    // scatter into LDS, sorted by bin
    #pragma unroll
    for (int j = 0; j < P1_EPT; ++j) {
        if (bn[j] >= 0) {
            int p = loff[bn[j]] + atomicAdd(&lrank[bn[j]], 1);
            sbuf[p] = ed[j];
            sbin[p] = (unsigned short)bn[j];
        }
    }
    __syncthreads();
    // coalesced writeout: position i belongs to bin sbin[i], local idx i-loff
    int m = min(E - base, P1_CHUNK);
    for (int i = tid; i < m; i += 256) {
        uint2 u = sbuf[i];
        int b = sbin[i];
        int dst = gbase[b] + (i - loff[b]);
        if (dst < BCAP) binned[(size_t)b * BCAP + dst] = u;
    }
}

// ---- exclusive scan of bin counts (single block) ---------------------------
__global__ void tpn_binscan(const int* __restrict__ binCur, int* __restrict__ binOff,
                            int NB) {
    __shared__ int sh[NB_MAX];
    int t = threadIdx.x;
    int v = (t < NB) ? min(binCur[t], BCAP) : 0;
    sh[t] = v;
    __syncthreads();
    for (int st = 1; st < NB_MAX; st <<= 1) {
        int u = (t >= st) ? sh[t - st] : 0;
        __syncthreads();
        sh[t] += u;
        __syncthreads();
    }
    if (t < NB) binOff[t] = sh[t] - v;
}

// ---- pass 2: per-bin packed CSR build + dis --------------------------------
__global__ void tpn_build(const uint2* __restrict__ binned, const int* __restrict__ binCur,
                          const int* __restrict__ binOff, uint2* __restrict__ packed,
                          int* __restrict__ off, int* __restrict__ cnt,
                          float* __restrict__ dis, int N) {
    __shared__ int   lcnt[256];
    __shared__ int   loff[256];
    __shared__ int   lrank[256];
    __shared__ int   lincl[256];
    __shared__ float ldeg[256];
    int b = blockIdx.x, tid = threadIdx.x;
    int m = min(binCur[b], BCAP);
    const uint2* src = binned + (size_t)b * BCAP;
    lcnt[tid] = 0; lrank[tid] = 0; ldeg[tid] = 0.0f;
    __syncthreads();
    for (int i = tid; i < m; i += 256) {
        uint2 u = src[i];
        int ln = u.x >> 17;
        atomicAdd(&lcnt[ln], 1);
        atomicAdd(&ldeg[ln], __uint_as_float(u.y));
    }
    __syncthreads();
    lincl[tid] = lcnt[tid];
    __syncthreads();
    for (int st = 1; st < 256; st <<= 1) {
        int u = (tid >= st) ? lincl[tid - st] : 0;
        __syncthreads();
        lincl[tid] += u;
        __syncthreads();
    }
    int excl = lincl[tid] - lcnt[tid];
    loff[tid] = excl;
    int node = (b << 8) + tid;
    if (node < N) {
        off[node] = binOff[b] + excl;
        cnt[node] = lcnt[tid];
        float s = ldeg[tid];
        dis[node] = (s > 0.0f) ? rsqrtf(fmaxf(s, 1e-12f)) : 0.0f;
    }
    __syncthreads();
    int gbase = binOff[b];
    for (int i = tid; i < m; i += 256) {
        uint2 u = src[i];
        int ln = u.x >> 17;
        int rk = atomicAdd(&lrank[ln], 1);
        packed[gbase + loff[ln] + rk] = make_uint2(u.x & 0x1FFFF, u.y);
    }
}

// ---- tiled GEMM: Y[n,f] = dis[n] * sum_k X[n,k]*W[k,f]; 64x64 tile ---------
// K must be a multiple of 64 (128 or 64 here).
__global__ __launch_bounds__(256, 4)
void tpn_gemm_t(const float* __restrict__ X, const float* __restrict__ W,
                const float* __restrict__ dis, float* __restrict__ Y,
                int N, int K) {
    __shared__ float sX[64][68];
    __shared__ float sW[64][64];
    const int t  = threadIdx.x;
    const int r  = t >> 4;
    const int cc = t & 15;
    const int fg = t & 15;
    const int ng = t >> 4;
    const int nb = blockIdx.x * 64;

    float acc[4][4] = {{0.f}};

    for (int kc = 0; kc < K; kc += 64) {
        __syncthreads();
        #pragma unroll
        for (int p = 0; p < 4; ++p) {
            int n = nb + r + p * 16;
            int ns = (n < N) ? n : (N - 1);
            float4 v = *reinterpret_cast<const float4*>(X + (size_t)ns * K + kc + 4 * cc);
            *reinterpret_cast<float4*>(&sX[r + p * 16][4 * cc]) = v;
        }
        #pragma unroll
        for (int p = 0; p < 4; ++p) {
            int k = kc + r + p * 16;
            float4 v = *reinterpret_cast<const float4*>(W + (size_t)k * 64 + 4 * cc);
            *reinterpret_cast<float4*>(&sW[r + p * 16][4 * cc]) = v;
        }
        __syncthreads();
        #pragma unroll 4
        for (int k = 0; k < 64; ++k) {
            float4 wv = *reinterpret_cast<const float4*>(&sW[k][4 * fg]);
            float x0 = sX[4 * ng + 0][k];
            float x1 = sX[4 * ng + 1][k];
            float x2 = sX[4 * ng + 2][k];
            float x3 = sX[4 * ng + 3][k];
            acc[0][0] = fmaf(x0, wv.x, acc[0][0]);
            acc[0][1] = fmaf(x0, wv.y, acc[0][1]);
            acc[0][2] = fmaf(x0, wv.z, acc[0][2]);
            acc[0][3] = fmaf(x0, wv.w, acc[0][3]);
            acc[1][0] = fmaf(x1, wv.x, acc[1][0]);
            acc[1][1] = fmaf(x1, wv.y, acc[1][1]);
            acc[1][2] = fmaf(x1, wv.z, acc[1][2]);
            acc[1][3] = fmaf(x1, wv.w, acc[1][3]);
            acc[2][0] = fmaf(x2, wv.x, acc[2][0]);
            acc[2][1] = fmaf(x2, wv.y, acc[2][1]);
            acc[2][2] = fmaf(x2, wv.z, acc[2][2]);
            acc[2][3] = fmaf(x2, wv.w, acc[2][3]);
            acc[3][0] = fmaf(x3, wv.x, acc[3][0]);
            acc[3][1] = fmaf(x3, wv.y, acc[3][1]);
            acc[3][2] = fmaf(x3, wv.z, acc[3][2]);
            acc[3][3] = fmaf(x3, wv.w, acc[3][3]);
        }
    }
    #pragma unroll
    for (int i = 0; i < 4; ++i) {
        int n = nb + 4 * ng + i;
        if (n < N) {
            float d = dis[n];
            float4 v = make_float4(acc[i][0] * d, acc[i][1] * d,
                                   acc[i][2] * d, acc[i][3] * d);
            *reinterpret_cast<float4*>(Y + (size_t)n * 64 + 4 * fg) = v;
        }
    }
}

// ---- aggregate: wave per node, 16 lanes x float4, 4 edges per gather instr -
// Hin rows pre-scaled by dis[row] (GEMM epilogue); epilogue applies dis[col]
// then bias/relu (+ optional sigmoid score gate).
template <bool FUSE_SCORE>
__global__ __launch_bounds__(256)
void tpn_agg(const uint2* __restrict__ packed, const int* __restrict__ off,
             const int* __restrict__ cnt, const float* __restrict__ dis,
             const float* __restrict__ Hin, const float* __restrict__ bias,
             const float* __restrict__ pw, const float* __restrict__ pb,
             float* __restrict__ Hout, int N) {
    int wid = (blockIdx.x * blockDim.x + threadIdx.x) >> 6;
    int lane = threadIdx.x & 63;
    if (wid >= N) return;
    const int eg = lane >> 4;        // edge slot 0..3
    const int fb = (lane & 15) * 4;  // feature base: fb..fb+3
    int start = off[wid], n = cnt[wid];
    const uint2* b = packed + start;
    const float* hp = Hin + fb;

    float4 A0 = {0.f, 0.f, 0.f, 0.f};
    float4 A1 = {0.f, 0.f, 0.f, 0.f};
    int j = 0;
    for (; j + 8 <= n; j += 8) {
        uint2 p0 = b[j + eg];
        uint2 p1 = b[j + 4 + eg];
        float4 v0 = *reinterpret_cast<const float4*>(hp + (size_t)p0.x * 64);
        float4 v1 = *reinterpret_cast<const float4*>(hp + (size_t)p1.x * 64);
        float w0 = __uint_as_float(p0.y);
        float w1 = __uint_as_float(p1.y);
        A0.x = fmaf(w0, v0.x, A0.x); A0.y = fmaf(w0, v0.y, A0.y);
        A0.z = fmaf(w0, v0.z, A0.z); A0.w = fmaf(w0, v0.w, A0.w);
        A1.x = fmaf(w1, v1.x, A1.x); A1.y = fmaf(w1, v1.y, A1.y);
        A1.z = fmaf(w1, v1.z, A1.z); A1.w = fmaf(w1, v1.w, A1.w);
    }
    for (; j < n; j += 4) {
        int idx = j + eg;
        uint2 p = (idx < n) ? b[idx] : make_uint2(0u, 0u);  // w=0 for pad lanes
        float4 v = *reinterpret_cast<const float4*>(hp + (size_t)p.x * 64);
        float w = __uint_as_float(p.y);
        A0.x = fmaf(w, v.x, A0.x); A0.y = fmaf(w, v.y, A0.y);
        A0.z = fmaf(w, v.z, A0.z); A0.w = fmaf(w, v.w, A0.w);
    }
    float4 acc;
    acc.x = A0.x + A1.x; acc.y = A0.y + A1.y;
    acc.z = A0.z + A1.z; acc.w = A0.w + A1.w;
    // fold the 4 edge slots (lanes ^16, ^32)
    acc.x += __shfl_xor(acc.x, 16); acc.x += __shfl_xor(acc.x, 32);
    acc.y += __shfl_xor(acc.y, 16); acc.y += __shfl_xor(acc.y, 32);
    acc.z += __shfl_xor(acc.z, 16); acc.z += __shfl_xor(acc.z, 32);
    acc.w += __shfl_xor(acc.w, 16); acc.w += __shfl_xor(acc.w, 32);

    float dc = dis[wid];
    const float4 bv = *reinterpret_cast<const float4*>(bias + fb);
    float4 h;
    h.x = fmaxf(fmaf(acc.x, dc, bv.x), 0.0f);
    h.y = fmaxf(fmaf(acc.y, dc, bv.y), 0.0f);
    h.z = fmaxf(fmaf(acc.z, dc, bv.z), 0.0f);
    h.w = fmaxf(fmaf(acc.w, dc, bv.w), 0.0f);
    if (FUSE_SCORE) {
        const float4 pv = *reinterpret_cast<const float4*>(pw + fb);
        float t = h.x * pv.x + h.y * pv.y + h.z * pv.z + h.w * pv.w;
        #pragma unroll
        for (int m = 1; m <= 8; m <<= 1) t += __shfl_xor(t, m);  // within 16-lane group
        float s = 1.0f / (1.0f + expf(-(t + pb[0])));
        h.x *= s; h.y *= s; h.z *= s; h.w *= s;
    }
    if (eg == 0)
        *reinterpret_cast<float4*>(Hout + (size_t)wid * 64 + fb) = h;
}

// ---- per-graph max || mean pooling (batch sorted) --------------------------
__global__ void tpn_pool(const float* __restrict__ Hs, const int* __restrict__ batch,
                         int N, float* __restrict__ Gf) {
    int g = blockIdx.x;
    int s, e;
    {
        int lo = 0, hi = N;
        while (lo < hi) { int mid = (lo + hi) >> 1; if (batch[mid] < g) lo = mid + 1; else hi = mid; }
        s = lo;
        lo = 0; hi = N;
        while (lo < hi) { int mid = (lo + hi) >> 1; if (batch[mid] < g + 1) lo = mid + 1; else hi = mid; }
        e = lo;
    }
    int lane = threadIdx.x & 63;
    int w = threadIdx.x >> 6;  // 0..3
    float mx = -3.4e38f, sm = 0.0f;
    for (int i = s + w; i < e; i += 4) {
        float v = Hs[(size_t)i * 64 + lane];
        mx = fmaxf(mx, v);
        sm += v;
    }
    __shared__ float shm[4][64], shs[4][64];
    shm[w][lane] = mx; shs[w][lane] = sm;
    __syncthreads();
    if (w == 0) {
        mx = fmaxf(fmaxf(shm[0][lane], shm[1][lane]), fmaxf(shm[2][lane], shm[3][lane]));
        sm = shs[0][lane] + shs[1][lane] + shs[2][lane] + shs[3][lane];
        float c = (float)(e - s);
        float inv = 1.0f / fmaxf(c, 1.0f);
        Gf[g * 128 + lane]      = mx;
        Gf[g * 128 + 64 + lane] = sm * inv;
    }
}

// ---- final MLP: out = relu(G @ lw1 + lb1) @ lw2 + lb2 ----------------------
__global__ void tpn_mlp(const float* __restrict__ Gf, const float* __restrict__ lw1,
                        const float* __restrict__ lb1, const float* __restrict__ lw2,
                        const float* __restrict__ lb2, float* __restrict__ out,
                        int G, int C) {
    int wid = (blockIdx.x * blockDim.x + threadIdx.x) >> 6;
    int lane = threadIdx.x & 63;
    if (wid >= G) return;
    const float* gr = Gf + (size_t)wid * 128;
    float acc = lb1[lane];
    for (int k = 0; k < 128; k += 4) {
        float4 gv = *reinterpret_cast<const float4*>(gr + k);
        acc = fmaf(gv.x, lw1[(k + 0) * 64 + lane], acc);
        acc = fmaf(gv.y, lw1[(k + 1) * 64 + lane], acc);
        acc = fmaf(gv.z, lw1[(k + 2) * 64 + lane], acc);
        acc = fmaf(gv.w, lw1[(k + 3) * 64 + lane], acc);
    }
    float t = fmaxf(acc, 0.0f);
    for (int c = 0; c < C; ++c) {
        float v = t * lw2[lane * C + c];
        #pragma unroll
        for (int m = 32; m > 0; m >>= 1) v += __shfl_xor(v, m);
        if (lane == 0) out[wid * C + c] = v + lb2[c];
    }
}

// ---------------------------------------------------------------------------
extern "C" void kernel_launch(void* const* d_in, const int* in_sizes, int n_in,
                              void* d_out, int out_size, void* d_ws, size_t ws_size,
                              hipStream_t stream) {
    const float* x   = (const float*)d_in[0];
    const int*   ei  = (const int*)  d_in[1];
    const float* ew  = (const float*)d_in[2];
    const int*   bat = (const int*)  d_in[3];
    const float* W1  = (const float*)d_in[5];
    const float* b1  = (const float*)d_in[6];
    const float* W2  = (const float*)d_in[7];
    const float* b2  = (const float*)d_in[8];
    const float* pw  = (const float*)d_in[9];
    const float* pb  = (const float*)d_in[10];
    const float* lw1 = (const float*)d_in[11];
    const float* lb1 = (const float*)d_in[12];
    const float* lw2 = (const float*)d_in[13];
    const float* lb2 = (const float*)d_in[14];
    float* out = (float*)d_out;

    const int N  = in_sizes[3];
    const int E  = in_sizes[2];
    const int IN = in_sizes[0] / N;   // 128
    const int C  = in_sizes[14];      // 2
    const int G  = out_size / C;      // 128
    const int NB = (N + 255) >> 8;    // bins of 256 nodes

    // ---- workspace layout ----
    char* ws = (char*)d_ws;
    size_t o = 0;
    auto alloc = [&](size_t bytes) { void* p = ws + o; o = (o + bytes + 255) & ~(size_t)255; return p; };
    int*   off    = (int*)  alloc((size_t)N * 4);
    int*   cnt    = (int*)  alloc((size_t)N * 4);
    float* dis    = (float*)alloc((size_t)N * 4);
    int*   binCur = (int*)  alloc((size_t)NB_MAX * 4);
    int*   binOff = (int*)  alloc((size_t)NB_MAX * 4);
    float* Gf     = (float*)alloc((size_t)G * 128 * 4);
    uint2* packed = (uint2*)alloc((size_t)E * 8);
    float* hA     = (float*)alloc((size_t)N * 64 * 4);
    float* hB     = (float*)alloc((size_t)N * 64 * 4);
    // binned is dead after tpn_build -> alias it over hA/hB
    uint2* binned = (uint2*)hA;
    (void)n_in; (void)ws_size;

    (void)hipMemsetAsync(binCur, 0, (size_t)NB_MAX * 4, stream);

    const int p1b   = (E + P1_CHUNK - 1) / P1_CHUNK;
    const int ggrid = (N + 63) / 64;                        // gemm tiles
    const int agrid = (N * 64 + TPN_BLK - 1) / TPN_BLK;     // wave per node

    // CSR build: bin (LDS sort, coalesced) -> scan -> build
    tpn_bin<<<p1b, TPN_BLK, 0, stream>>>(ei, ew, binCur, binned, E, NB);
    tpn_binscan<<<1, NB_MAX, 0, stream>>>(binCur, binOff, NB);
    tpn_build<<<NB, 256, 0, stream>>>(binned, binCur, binOff, packed, off, cnt, dis, N);

    // layer 1: hA = dis * (x @ W1) ; hB = relu(dis*agg(hA) + b1)
    tpn_gemm_t<<<ggrid, 256, 0, stream>>>(x, W1, dis, hA, N, IN);
    tpn_agg<false><<<agrid, TPN_BLK, 0, stream>>>(packed, off, cnt, dis, hA, b1, pw, pb, hB, N);

    // layer 2: hA = dis * (hB @ W2) ; hB = score-gated relu(dis*agg(hA) + b2)
    tpn_gemm_t<<<ggrid, 256, 0, stream>>>(hB, W2, dis, hA, N, 64);
    tpn_agg<true><<<agrid, TPN_BLK, 0, stream>>>(packed, off, cnt, dis, hA, b2, pw, pb, hB, N);

    // pooling + MLP head
    tpn_pool<<<G, TPN_BLK, 0, stream>>>(hB, bat, N, Gf);
    tpn_mlp<<<(G * 64 + TPN_BLK - 1) / TPN_BLK, TPN_BLK, 0, stream>>>(Gf, lw1, lb1, lw2, lb2, out, G, C);
}